// Round 5
// baseline (709.330 us; speedup 1.0000x reference)
//
#include <hip/hip_runtime.h>
#include <hip/hip_cooperative_groups.h>

namespace cg = cooperative_groups;

// GCN: h1 = relu(Agg(x@W1)+b1); h2 = relu(Agg(h1@W2)+b2); out = mean(h2)@Wc+bc
// Agg uses norm(r,c)=dinv[r]*dinv[c] which factors: prescale rows by dinv in
// GEMM epilogue, pull-accumulate via CSR (built per call), postscale+bias+relu.
// R1: k_agg MLP — float4 lanes, half-wave/edge, 4-deep unroll. (88->57us)
// R2: edge-kernel x4 ILP — NEUTRAL (falsified latency theory).
// R3: 8-plane contention split — NEUTRAL (falsified line-contention theory).
// R4: scattered DEVICE-scope atomics are a fixed ~15 G/s memory-side ceiling.
//     Fused cooperative k_build: XCD-private histograms (HW_REG_XCC_ID) +
//     WORKGROUP-scope atomics => executed in local XCD L2. Same resident
//     block does count and bucket phases (cooperative => no XCD migration);
//     __threadfence()+grid.sync() for cross-XCD visibility between phases.

constexpr int N = 50000;
constexpr int E = 800000;
constexpr int D = 128;
constexpr int DOUT = 40;
constexpr int NXCD = 8;
constexpr int NBINS = N * NXCD;              // 400000, bin = c*8 + xcd
constexpr int G = 512;                       // cooperative grid blocks
constexpr int CHUNK_E = (E + G - 1) / G;     // 1563 edges per block
constexpr int NB1 = (NBINS + 1023) / 1024;   // 391 scan-active blocks

__device__ __forceinline__ int xcc_id() {
    int id;
    asm volatile("s_getreg_b32 %0, hwreg(HW_REG_XCC_ID)" : "=s"(id));
    return id & (NXCD - 1);
}

// ---------------- Fused CSR build (cooperative) ----------------
// cnt: [NXCD][N] plane-major histogram, reused as cursor. Pre-zeroed by memset.
// binofs: [NBINS] bin-major (c*8+xcd) exclusive offsets (read by k_node).
// bsum: [G] per-scan-block totals.
__global__ __launch_bounds__(256) void k_build(const int* __restrict__ ei,
                                               int* __restrict__ cnt,
                                               int* __restrict__ binofs,
                                               int* __restrict__ bsum,
                                               int* __restrict__ csr) {
    cg::grid_group grid = cg::this_grid();
    __shared__ int sbuf[256];
    int b = blockIdx.x, t = threadIdx.x;
    int xcd = xcc_id();
    int* mycnt = cnt + xcd * N;

    int e0 = b * CHUNK_E;
    int e1 = e0 + CHUNK_E;
    if (e1 > E) e1 = E;

    // ---- phase 1: count into XCD-private plane (local-L2 atomics) ----
    for (int e = e0 + t; e < e1; e += 256) {
        int c = ei[E + e];
        __hip_atomic_fetch_add(&mycnt[c], 1, __ATOMIC_RELAXED,
                               __HIP_MEMORY_SCOPE_WORKGROUP);
    }
    __threadfence();
    grid.sync();

    // ---- phase 2: block-local exclusive scan over 1024 bins ----
    // bin = c*8+xcd (c-major so each node's CSR segment is contiguous)
    int v0 = 0, v1 = 0, v2 = 0, v3 = 0, excl = 0;
    int base = b * 1024 + t * 4;
    if (b < NB1) {
        if (base + 0 < NBINS) v0 = cnt[((base + 0) & 7) * N + ((base + 0) >> 3)];
        if (base + 1 < NBINS) v1 = cnt[((base + 1) & 7) * N + ((base + 1) >> 3)];
        if (base + 2 < NBINS) v2 = cnt[((base + 2) & 7) * N + ((base + 2) >> 3)];
        if (base + 3 < NBINS) v3 = cnt[((base + 3) & 7) * N + ((base + 3) >> 3)];
        int s = v0 + v1 + v2 + v3;
        sbuf[t] = s;
        __syncthreads();
        for (int d = 1; d < 256; d <<= 1) {
            int add = (t >= d) ? sbuf[t - d] : 0;
            __syncthreads();
            sbuf[t] += add;
            __syncthreads();
        }
        excl = sbuf[t] - s;                  // block-local exclusive offset
        if (t == 255) bsum[b] = sbuf[255];
    }
    __threadfence();
    grid.sync();

    // ---- phase 3: block prefix over bsum, write binofs + cursor init ----
    if (b < NB1) {
        int x = 0;
        if (t < b) x += bsum[t];
        if (t + 256 < b) x += bsum[t + 256];
        __syncthreads();                     // sbuf reuse safe
        sbuf[t] = x;
        __syncthreads();
        for (int d = 128; d > 0; d >>= 1) {
            if (t < d) sbuf[t] += sbuf[t + d];
            __syncthreads();
        }
        int off = sbuf[0] + excl;
        if (base + 0 < NBINS) { binofs[base + 0] = off; cnt[((base + 0) & 7) * N + ((base + 0) >> 3)] = off; off += v0; }
        if (base + 1 < NBINS) { binofs[base + 1] = off; cnt[((base + 1) & 7) * N + ((base + 1) >> 3)] = off; off += v1; }
        if (base + 2 < NBINS) { binofs[base + 2] = off; cnt[((base + 2) & 7) * N + ((base + 2) >> 3)] = off; off += v2; }
        if (base + 3 < NBINS) { binofs[base + 3] = off; cnt[((base + 3) & 7) * N + ((base + 3) >> 3)] = off; off += v3; }
    }
    __threadfence();
    grid.sync();

    // ---- phase 4: bucket (same edges, same block => same XCD as phase 1) ----
    for (int e = e0 + t; e < e1; e += 256) {
        int c = ei[E + e];
        int r = ei[e];
        int p = __hip_atomic_fetch_add(&mycnt[c], 1, __ATOMIC_RELAXED,
                                       __HIP_MEMORY_SCOPE_WORKGROUP);
        csr[p] = r;
    }
}

__global__ void k_node(const int* __restrict__ binofs, int* __restrict__ nodeofs,
                       float* __restrict__ dinv) {
    int c = blockIdx.x * 256 + threadIdx.x;
    if (c >= N) return;
    int e0 = binofs[c * NXCD];
    int e1 = (c == N - 1) ? E : binofs[(c + 1) * NXCD];
    nodeofs[c] = e0;
    dinv[c] = rsqrtf((float)(e1 - e0 + 1));    // +1 self loop; always > 0
    if (c == 0) nodeofs[N] = E;
}

// ---------------- GEMM: out[r] = dinv[r] * (A[r] @ W) ----------------
__global__ __launch_bounds__(256) void k_gemm(const float* __restrict__ A,
                                              const float* __restrict__ W,
                                              const float* __restrict__ dinv,
                                              float* __restrict__ out, int M) {
    __shared__ float As[32][128];   // [k][row]
    __shared__ float Bs[32][128];   // [k][col]
    int tid = threadIdx.x;
    int tx = tid & 15, ty = tid >> 4;
    int row0 = blockIdx.x * 128;
    float acc[8][8] = {};

    for (int kt = 0; kt < 128; kt += 32) {
        {
            int r = tid >> 1;
            int kk = (tid & 1) * 16;
            int grow = row0 + r;
#pragma unroll
            for (int q = 0; q < 4; ++q) {
                float4 v = make_float4(0.f, 0.f, 0.f, 0.f);
                if (grow < M) v = *(const float4*)&A[(size_t)grow * D + kt + kk + q * 4];
                As[kk + q * 4 + 0][r] = v.x;
                As[kk + q * 4 + 1][r] = v.y;
                As[kk + q * 4 + 2][r] = v.z;
                As[kk + q * 4 + 3][r] = v.w;
            }
        }
        {
            int kb = tid >> 3;
            int cb = (tid & 7) * 16;
#pragma unroll
            for (int q = 0; q < 4; ++q) {
                *(float4*)&Bs[kb][cb + q * 4] =
                    *(const float4*)&W[(size_t)(kt + kb) * D + cb + q * 4];
            }
        }
        __syncthreads();
#pragma unroll
        for (int k = 0; k < 32; ++k) {
            float a[8], bb[8];
            *(float4*)&a[0] = *(const float4*)&As[k][ty * 8];
            *(float4*)&a[4] = *(const float4*)&As[k][ty * 8 + 4];
            *(float4*)&bb[0] = *(const float4*)&Bs[k][tx * 8];
            *(float4*)&bb[4] = *(const float4*)&Bs[k][tx * 8 + 4];
#pragma unroll
            for (int i = 0; i < 8; ++i)
#pragma unroll
                for (int j = 0; j < 8; ++j)
                    acc[i][j] = fmaf(a[i], bb[j], acc[i][j]);
        }
        __syncthreads();
    }

#pragma unroll
    for (int i = 0; i < 8; ++i) {
        int r = row0 + ty * 8 + i;
        if (r < M) {
            float s = dinv[r];
#pragma unroll
            for (int j = 0; j < 8; j += 4) {
                float4 v;
                v.x = acc[i][j + 0] * s;
                v.y = acc[i][j + 1] * s;
                v.z = acc[i][j + 2] * s;
                v.w = acc[i][j + 3] * s;
                *(float4*)&out[(size_t)r * D + tx * 8 + j] = v;
            }
        }
    }
}

// ---------------- Aggregation (pull, 1 wave per node, MLP-optimized) ------
__device__ __forceinline__ void f4add(float4& a, const float4& v) {
    a.x += v.x; a.y += v.y; a.z += v.z; a.w += v.w;
}

__global__ __launch_bounds__(256) void k_agg(const float4* __restrict__ hs4,
                                             const int* __restrict__ ofs,
                                             const int* __restrict__ csr,
                                             const float* __restrict__ dinv,
                                             const float4* __restrict__ bias4,
                                             float4* __restrict__ out4) {
    int wave = threadIdx.x >> 6;
    int lane = threadIdx.x & 63;
    int h = lane >> 5;          // half-wave id 0/1
    int q = lane & 31;          // float4 column
    int c = blockIdx.x * 4 + wave;
    if (c >= N) return;
    int e0 = ofs[c], e1 = ofs[c + 1];

    float4 z = make_float4(0.f, 0.f, 0.f, 0.f);
    float4 a0 = z, a1 = z, a2 = z, a3 = z;
    if (h == 0) a0 = hs4[(size_t)c * 32 + q];        // self loop on half 0

    int j = e0;
    for (; j + 8 <= e1; j += 8) {
        int r0 = csr[j + 0 + h];
        int r1 = csr[j + 2 + h];
        int r2 = csr[j + 4 + h];
        int r3 = csr[j + 6 + h];
        float4 v0 = hs4[(size_t)r0 * 32 + q];
        float4 v1 = hs4[(size_t)r1 * 32 + q];
        float4 v2 = hs4[(size_t)r2 * 32 + q];
        float4 v3 = hs4[(size_t)r3 * 32 + q];
        f4add(a0, v0); f4add(a1, v1); f4add(a2, v2); f4add(a3, v3);
    }
    if (j + 4 <= e1) {
        int r0 = csr[j + 0 + h];
        int r1 = csr[j + 2 + h];
        float4 v0 = hs4[(size_t)r0 * 32 + q];
        float4 v1 = hs4[(size_t)r1 * 32 + q];
        f4add(a0, v0); f4add(a1, v1);
        j += 4;
    }
    if (j + 2 <= e1) {
        int r0 = csr[j + h];
        float4 v0 = hs4[(size_t)r0 * 32 + q];
        f4add(a0, v0);
        j += 2;
    }
    if (j < e1 && h == 0) {
        int r0 = csr[j];
        float4 v0 = hs4[(size_t)r0 * 32 + q];
        f4add(a0, v0);
    }

    f4add(a0, a1); f4add(a2, a3); f4add(a0, a2);
    a0.x += __shfl_xor(a0.x, 32, 64);
    a0.y += __shfl_xor(a0.y, 32, 64);
    a0.z += __shfl_xor(a0.z, 32, 64);
    a0.w += __shfl_xor(a0.w, 32, 64);

    if (h == 0) {
        float dc = dinv[c];
        float4 b = bias4[q];
        float4 o;
        o.x = fmaxf(fmaf(dc, a0.x, b.x), 0.f);
        o.y = fmaxf(fmaf(dc, a0.y, b.y), 0.f);
        o.z = fmaxf(fmaf(dc, a0.z, b.z), 0.f);
        o.w = fmaxf(fmaf(dc, a0.w, b.w), 0.f);
        out4[(size_t)c * 32 + q] = o;
    }
}

// ---------------- Mean pool (stage 1) ----------------
__global__ __launch_bounds__(256) void k_pool(const float* __restrict__ h,
                                              float* __restrict__ gpart) {
    int d = threadIdx.x & 127;
    int half = threadIdx.x >> 7;
    int b = blockIdx.x;                 // 256 blocks
    int per = (N + 255) / 256;          // 196
    int r0 = b * per;
    int r1 = r0 + per;
    if (r1 > N) r1 = N;
    float acc = 0.f;
    for (int r = r0 + half; r < r1; r += 2)
        acc += h[(size_t)r * D + d];
    __shared__ float red[256];
    red[threadIdx.x] = acc;
    __syncthreads();
    if (half == 0) gpart[(size_t)b * D + d] = red[d] + red[128 + d];
}

// ---------------- Final: g = sum(gpart)/N; out = g@Wc + bc  (512 threads)
__global__ __launch_bounds__(512) void k_final(const float* __restrict__ gpart,
                                               const float* __restrict__ Wc,
                                               const float* __restrict__ bc,
                                               float* __restrict__ out) {
    __shared__ float g[D];
    __shared__ float red[512];
    int t = threadIdx.x;
    int d = t & 127, grp = t >> 7;      // 4 groups, 64 partials each
    float s = 0.f;
#pragma unroll 4
    for (int w = grp * 64; w < grp * 64 + 64; ++w)
        s += gpart[(size_t)w * D + d];
    red[t] = s;
    __syncthreads();
    if (grp == 0)
        g[d] = (red[d] + red[128 + d] + red[256 + d] + red[384 + d]) * (1.0f / (float)N);
    __syncthreads();
    if (t < DOUT) {
        float acc = bc[t];
        for (int dd = 0; dd < D; ++dd) acc = fmaf(g[dd], Wc[dd * DOUT + t], acc);
        out[t] = acc;
    }
}

extern "C" void kernel_launch(void* const* d_in, const int* in_sizes, int n_in,
                              void* d_out, int out_size, void* d_ws, size_t ws_size,
                              hipStream_t stream) {
    const float* x  = (const float*)d_in[0];
    const int*   ei = (const int*)d_in[1];
    const float* W1 = (const float*)d_in[2];
    const float* b1 = (const float*)d_in[3];
    const float* W2 = (const float*)d_in[4];
    const float* b2 = (const float*)d_in[5];
    const float* Wc = (const float*)d_in[6];
    const float* bc = (const float*)d_in[7];
    float* out = (float*)d_out;

    char* ws = (char*)d_ws;
    size_t off = 0;
    auto alloc = [&](size_t bytes) {
        void* p = ws + off;
        off += (bytes + 511) & ~(size_t)511;
        return p;
    };
    int*   cnt8    = (int*)  alloc((size_t)NBINS * 4);   // reused as cursor
    int*   binofs  = (int*)  alloc((size_t)NBINS * 4);
    int*   nodeofs = (int*)  alloc((size_t)(N + 1) * 4);
    float* dinv    = (float*)alloc((size_t)N * 4);
    int*   bsum    = (int*)  alloc((size_t)G * 4);
    int*   csr     = (int*)  alloc((size_t)E * 4);
    float* hsA     = (float*)alloc((size_t)N * D * 4);
    float* hactB   = (float*)alloc((size_t)N * D * 4);
    float* gpart   = (float*)alloc((size_t)256 * D * 4);
    (void)ws_size; (void)in_sizes; (void)n_in; (void)out_size;

    hipMemsetAsync(cnt8, 0, (size_t)NBINS * 4, stream);

    {
        void* args[] = {(void*)&ei, (void*)&cnt8, (void*)&binofs,
                        (void*)&bsum, (void*)&csr};
        hipLaunchCooperativeKernel((const void*)k_build, dim3(G), dim3(256),
                                   args, 0, stream);
    }
    k_node<<<(N + 255) / 256, 256, 0, stream>>>(binofs, nodeofs, dinv);

    int gM = (N + 127) / 128;   // 391
    int gA = (N + 3) / 4;       // 12500

    // layer 1
    k_gemm<<<gM, 256, 0, stream>>>(x, W1, dinv, hsA, N);
    k_agg<<<gA, 256, 0, stream>>>((const float4*)hsA, nodeofs, csr, dinv,
                                  (const float4*)b1, (float4*)hactB);
    // layer 2
    k_gemm<<<gM, 256, 0, stream>>>(hactB, W2, dinv, hsA, N);
    k_agg<<<gA, 256, 0, stream>>>((const float4*)hsA, nodeofs, csr, dinv,
                                  (const float4*)b2, (float4*)hactB);
    // pool + classify
    k_pool<<<256, 256, 0, stream>>>(hactB, gpart);
    k_final<<<1, 512, 0, stream>>>(gpart, Wc, bc, out);
}

// Round 6
// 339.245 us; speedup vs baseline: 2.0909x; 2.0909x over previous
//
#include <hip/hip_runtime.h>

// GCN: h1 = relu(Agg(x@W1)+b1); h2 = relu(Agg(h1@W2)+b2); out = mean(h2)@Wc+bc
// norm(r,c)=dinv[r]*dinv[c] factors: dinv[r] applied in agg inner loop,
// dinv[c] in agg epilogue.
// R1: k_agg MLP — float4 lanes, half-wave/edge, 4-deep unroll. (88->57us)
// R2: edge-kernel x4 ILP — NEUTRAL (falsified latency theory).
// R3: 8-plane contention split — NEUTRAL (falsified line-contention theory).
// R4: coop kernel + WG-scope atomics — REGRESSED 709us (falsified scope theory).
// R5: scattered atomics are a fixed ~14 G/s ceiling => do ONE atomic pass, not
//     two: fixed-capacity buckets (CAP=64, uint16 csr) kill count+scan; hide
//     the bucket pass by grid-fusing it with GEMM-1 (independent work, atomic-
//     bound waves overlap VALU-bound waves).

constexpr int N = 50000;
constexpr int E = 800000;
constexpr int D = 128;
constexpr int DOUT = 40;
constexpr int CAP = 64;              // bucket capacity (Poisson(16) tail ~1e-18)
constexpr int T4 = E / 4;            // 200000 bucket threads
constexpr int GB = (T4 + 255) / 256; // 782 bucket blocks
constexpr int GM = (N + 127) / 128;  // 391 gemm blocks

// ---------------- Fused: bucket-scatter + GEMM layer 1 ----------------
// blocks [0,GB): bucket edges into per-node fixed slots (1 atomic pass)
// blocks [GB,GB+GM): outh[r] = A[r] @ W  (128x128 tile, no prescale)
__global__ __launch_bounds__(256) void k_fuse(const int* __restrict__ ei,
                                              int* __restrict__ cursor,
                                              unsigned short* __restrict__ csr,
                                              const float* __restrict__ A,
                                              const float* __restrict__ W,
                                              float* __restrict__ outh) {
    __shared__ float As[32][128];   // [k][row]
    __shared__ float Bs[32][128];   // [k][col]

    if (blockIdx.x < GB) {
        // ---- bucket branch (atomic-bound; overlaps with gemm waves) ----
        int t = blockIdx.x * 256 + threadIdx.x;
        if (t >= T4) return;
#pragma unroll
        for (int i = 0; i < 4; ++i) {
            int e = t + i * T4;
            int c = ei[E + e];
            int r = ei[e];
            int p = atomicAdd(&cursor[c], 1);
            if (p < CAP) csr[(c << 6) + p] = (unsigned short)r;
        }
        return;
    }

    // ---- gemm branch ----
    int tid = threadIdx.x;
    int tx = tid & 15, ty = tid >> 4;
    int row0 = (blockIdx.x - GB) * 128;
    float acc[8][8] = {};

    for (int kt = 0; kt < 128; kt += 32) {
        {
            int r = tid >> 1;
            int kk = (tid & 1) * 16;
            int grow = row0 + r;
#pragma unroll
            for (int q = 0; q < 4; ++q) {
                float4 v = make_float4(0.f, 0.f, 0.f, 0.f);
                if (grow < N) v = *(const float4*)&A[(size_t)grow * D + kt + kk + q * 4];
                As[kk + q * 4 + 0][r] = v.x;
                As[kk + q * 4 + 1][r] = v.y;
                As[kk + q * 4 + 2][r] = v.z;
                As[kk + q * 4 + 3][r] = v.w;
            }
        }
        {
            int kb = tid >> 3;
            int cb = (tid & 7) * 16;
#pragma unroll
            for (int q = 0; q < 4; ++q) {
                *(float4*)&Bs[kb][cb + q * 4] =
                    *(const float4*)&W[(size_t)(kt + kb) * D + cb + q * 4];
            }
        }
        __syncthreads();
#pragma unroll
        for (int k = 0; k < 32; ++k) {
            float a[8], bb[8];
            *(float4*)&a[0] = *(const float4*)&As[k][ty * 8];
            *(float4*)&a[4] = *(const float4*)&As[k][ty * 8 + 4];
            *(float4*)&bb[0] = *(const float4*)&Bs[k][tx * 8];
            *(float4*)&bb[4] = *(const float4*)&Bs[k][tx * 8 + 4];
#pragma unroll
            for (int i = 0; i < 8; ++i)
#pragma unroll
                for (int j = 0; j < 8; ++j)
                    acc[i][j] = fmaf(a[i], bb[j], acc[i][j]);
        }
        __syncthreads();
    }

#pragma unroll
    for (int i = 0; i < 8; ++i) {
        int r = row0 + ty * 8 + i;
        if (r < N) {
#pragma unroll
            for (int j = 0; j < 8; j += 4)
                *(float4*)&outh[(size_t)r * D + tx * 8 + j] =
                    make_float4(acc[i][j], acc[i][j + 1], acc[i][j + 2], acc[i][j + 3]);
        }
    }
}

// ---------------- Plain GEMM (layer 2): out[r] = A[r] @ W ----------------
__global__ __launch_bounds__(256) void k_gemm(const float* __restrict__ A,
                                              const float* __restrict__ W,
                                              float* __restrict__ out) {
    __shared__ float As[32][128];
    __shared__ float Bs[32][128];
    int tid = threadIdx.x;
    int tx = tid & 15, ty = tid >> 4;
    int row0 = blockIdx.x * 128;
    float acc[8][8] = {};

    for (int kt = 0; kt < 128; kt += 32) {
        {
            int r = tid >> 1;
            int kk = (tid & 1) * 16;
            int grow = row0 + r;
#pragma unroll
            for (int q = 0; q < 4; ++q) {
                float4 v = make_float4(0.f, 0.f, 0.f, 0.f);
                if (grow < N) v = *(const float4*)&A[(size_t)grow * D + kt + kk + q * 4];
                As[kk + q * 4 + 0][r] = v.x;
                As[kk + q * 4 + 1][r] = v.y;
                As[kk + q * 4 + 2][r] = v.z;
                As[kk + q * 4 + 3][r] = v.w;
            }
        }
        {
            int kb = tid >> 3;
            int cb = (tid & 7) * 16;
#pragma unroll
            for (int q = 0; q < 4; ++q) {
                *(float4*)&Bs[kb][cb + q * 4] =
                    *(const float4*)&W[(size_t)(kt + kb) * D + cb + q * 4];
            }
        }
        __syncthreads();
#pragma unroll
        for (int k = 0; k < 32; ++k) {
            float a[8], bb[8];
            *(float4*)&a[0] = *(const float4*)&As[k][ty * 8];
            *(float4*)&a[4] = *(const float4*)&As[k][ty * 8 + 4];
            *(float4*)&bb[0] = *(const float4*)&Bs[k][tx * 8];
            *(float4*)&bb[4] = *(const float4*)&Bs[k][tx * 8 + 4];
#pragma unroll
            for (int i = 0; i < 8; ++i)
#pragma unroll
                for (int j = 0; j < 8; ++j)
                    acc[i][j] = fmaf(a[i], bb[j], acc[i][j]);
        }
        __syncthreads();
    }

#pragma unroll
    for (int i = 0; i < 8; ++i) {
        int r = row0 + ty * 8 + i;
        if (r < N) {
#pragma unroll
            for (int j = 0; j < 8; j += 4)
                *(float4*)&out[(size_t)r * D + tx * 8 + j] =
                    make_float4(acc[i][j], acc[i][j + 1], acc[i][j + 2], acc[i][j + 3]);
        }
    }
}

// ---------------- dinv from bucket counts ----------------
__global__ void k_node(const int* __restrict__ cursor, float* __restrict__ dinv) {
    int c = blockIdx.x * 256 + threadIdx.x;
    if (c < N) dinv[c] = rsqrtf((float)(cursor[c] + 1));   // +1 self loop
}

// ---------------- Aggregation (pull, 1 wave per node, MLP-optimized) ------
// out[c] = relu(dinv[c] * (dinv[c]*h[c] + sum_r dinv[r]*h[r]) + bias)
__device__ __forceinline__ void f4fma(float4& a, float w, const float4& v) {
    a.x = fmaf(w, v.x, a.x); a.y = fmaf(w, v.y, a.y);
    a.z = fmaf(w, v.z, a.z); a.w = fmaf(w, v.w, a.w);
}
__device__ __forceinline__ void f4add(float4& a, const float4& v) {
    a.x += v.x; a.y += v.y; a.z += v.z; a.w += v.w;
}

__global__ __launch_bounds__(256) void k_agg(const float4* __restrict__ hs4,
                                             const int* __restrict__ deg,
                                             const unsigned short* __restrict__ csr,
                                             const float* __restrict__ dinv,
                                             const float4* __restrict__ bias4,
                                             float4* __restrict__ out4) {
    int wave = threadIdx.x >> 6;
    int lane = threadIdx.x & 63;
    int h = lane >> 5;          // half-wave id 0/1
    int q = lane & 31;          // float4 column
    int c = blockIdx.x * 4 + wave;
    if (c >= N) return;
    int dg = deg[c];
    if (dg > CAP) dg = CAP;
    int e0 = c << 6;
    int e1 = e0 + dg;
    float dc = dinv[c];

    float4 z = make_float4(0.f, 0.f, 0.f, 0.f);
    float4 a0 = z, a1 = z, a2 = z, a3 = z;
    if (h == 0) {                                    // self loop on half 0
        float4 v = hs4[(size_t)c * 32 + q];
        f4fma(a0, dc, v);
    }

    int j = e0;
    for (; j + 8 <= e1; j += 8) {
        int r0 = csr[j + 0 + h];
        int r1 = csr[j + 2 + h];
        int r2 = csr[j + 4 + h];
        int r3 = csr[j + 6 + h];
        float w0 = dinv[r0], w1 = dinv[r1], w2 = dinv[r2], w3 = dinv[r3];
        float4 v0 = hs4[(size_t)r0 * 32 + q];
        float4 v1 = hs4[(size_t)r1 * 32 + q];
        float4 v2 = hs4[(size_t)r2 * 32 + q];
        float4 v3 = hs4[(size_t)r3 * 32 + q];
        f4fma(a0, w0, v0); f4fma(a1, w1, v1); f4fma(a2, w2, v2); f4fma(a3, w3, v3);
    }
    if (j + 4 <= e1) {
        int r0 = csr[j + 0 + h];
        int r1 = csr[j + 2 + h];
        float w0 = dinv[r0], w1 = dinv[r1];
        float4 v0 = hs4[(size_t)r0 * 32 + q];
        float4 v1 = hs4[(size_t)r1 * 32 + q];
        f4fma(a0, w0, v0); f4fma(a1, w1, v1);
        j += 4;
    }
    if (j + 2 <= e1) {
        int r0 = csr[j + h];
        float w0 = dinv[r0];
        float4 v0 = hs4[(size_t)r0 * 32 + q];
        f4fma(a0, w0, v0);
        j += 2;
    }
    if (j < e1 && h == 0) {
        int r0 = csr[j];
        float w0 = dinv[r0];
        float4 v0 = hs4[(size_t)r0 * 32 + q];
        f4fma(a0, w0, v0);
    }

    f4add(a0, a1); f4add(a2, a3); f4add(a0, a2);
    a0.x += __shfl_xor(a0.x, 32, 64);
    a0.y += __shfl_xor(a0.y, 32, 64);
    a0.z += __shfl_xor(a0.z, 32, 64);
    a0.w += __shfl_xor(a0.w, 32, 64);

    if (h == 0) {
        float4 b = bias4[q];
        float4 o;
        o.x = fmaxf(fmaf(dc, a0.x, b.x), 0.f);
        o.y = fmaxf(fmaf(dc, a0.y, b.y), 0.f);
        o.z = fmaxf(fmaf(dc, a0.z, b.z), 0.f);
        o.w = fmaxf(fmaf(dc, a0.w, b.w), 0.f);
        out4[(size_t)c * 32 + q] = o;
    }
}

// ---------------- Mean pool (stage 1) ----------------
__global__ __launch_bounds__(256) void k_pool(const float* __restrict__ h,
                                              float* __restrict__ gpart) {
    int d = threadIdx.x & 127;
    int half = threadIdx.x >> 7;
    int b = blockIdx.x;                 // 256 blocks
    int per = (N + 255) / 256;          // 196
    int r0 = b * per;
    int r1 = r0 + per;
    if (r1 > N) r1 = N;
    float acc = 0.f;
    for (int r = r0 + half; r < r1; r += 2)
        acc += h[(size_t)r * D + d];
    __shared__ float red[256];
    red[threadIdx.x] = acc;
    __syncthreads();
    if (half == 0) gpart[(size_t)b * D + d] = red[d] + red[128 + d];
}

// ---------------- Final: g = sum(gpart)/N; out = g@Wc + bc  (512 threads)
__global__ __launch_bounds__(512) void k_final(const float* __restrict__ gpart,
                                               const float* __restrict__ Wc,
                                               const float* __restrict__ bc,
                                               float* __restrict__ out) {
    __shared__ float g[D];
    __shared__ float red[512];
    int t = threadIdx.x;
    int d = t & 127, grp = t >> 7;      // 4 groups, 64 partials each
    float s = 0.f;
#pragma unroll 4
    for (int w = grp * 64; w < grp * 64 + 64; ++w)
        s += gpart[(size_t)w * D + d];
    red[t] = s;
    __syncthreads();
    if (grp == 0)
        g[d] = (red[d] + red[128 + d] + red[256 + d] + red[384 + d]) * (1.0f / (float)N);
    __syncthreads();
    if (t < DOUT) {
        float acc = bc[t];
        for (int dd = 0; dd < D; ++dd) acc = fmaf(g[dd], Wc[dd * DOUT + t], acc);
        out[t] = acc;
    }
}

extern "C" void kernel_launch(void* const* d_in, const int* in_sizes, int n_in,
                              void* d_out, int out_size, void* d_ws, size_t ws_size,
                              hipStream_t stream) {
    const float* x  = (const float*)d_in[0];
    const int*   ei = (const int*)d_in[1];
    const float* W1 = (const float*)d_in[2];
    const float* b1 = (const float*)d_in[3];
    const float* W2 = (const float*)d_in[4];
    const float* b2 = (const float*)d_in[5];
    const float* Wc = (const float*)d_in[6];
    const float* bc = (const float*)d_in[7];
    float* out = (float*)d_out;

    char* ws = (char*)d_ws;
    size_t off = 0;
    auto alloc = [&](size_t bytes) {
        void* p = ws + off;
        off += (bytes + 511) & ~(size_t)511;
        return p;
    };
    int*            cursor = (int*)           alloc((size_t)N * 4);   // = deg
    unsigned short* csr    = (unsigned short*)alloc((size_t)N * CAP * 2);
    float*          dinv   = (float*)         alloc((size_t)N * 4);
    float*          hsA    = (float*)         alloc((size_t)N * D * 4);
    float*          hactB  = (float*)         alloc((size_t)N * D * 4);
    float*          gpart  = (float*)         alloc((size_t)256 * D * 4);
    (void)ws_size; (void)in_sizes; (void)n_in; (void)out_size;

    hipMemsetAsync(cursor, 0, (size_t)N * 4, stream);

    // fused: bucket (blocks 0..GB-1, starts first) + gemm layer 1
    k_fuse<<<GB + GM, 256, 0, stream>>>(ei, cursor, csr, x, W1, hsA);
    k_node<<<(N + 255) / 256, 256, 0, stream>>>(cursor, dinv);

    int gA = (N + 3) / 4;       // 12500
    // layer 1 aggregation
    k_agg<<<gA, 256, 0, stream>>>((const float4*)hsA, cursor, csr, dinv,
                                  (const float4*)b1, (float4*)hactB);
    // layer 2
    k_gemm<<<GM, 256, 0, stream>>>(hactB, W2, hsA);
    k_agg<<<gA, 256, 0, stream>>>((const float4*)hsA, cursor, csr, dinv,
                                  (const float4*)b2, (float4*)hactB);
    // pool + classify
    k_pool<<<256, 256, 0, stream>>>(hactB, gpart);
    k_final<<<1, 512, 0, stream>>>(gpart, Wc, bc, out);
}

// Round 7
// 272.339 us; speedup vs baseline: 2.6046x; 1.2457x over previous
//
#include <hip/hip_runtime.h>
#include <hip/hip_fp16.h>

// GCN: h1 = relu(Agg(x@W1)+b1); h2 = relu(Agg(h1@W2)+b2); out = mean(h2)@Wc+bc
// norm(r,c)=dinv[r]*dinv[c] factors; dinv computed inline as rsqrt(deg+1).
// R1: k_agg MLP float4/half-wave/4-deep (88->57us)
// R2: edge x4 ILP — NEUTRAL. R3: 8-plane split — NEUTRAL.
// R4: coop + WG-scope atomics — REGRESSED 709us.
// R5: one atomic pass (CAP=64 buckets, u16 csr) + bucket/gemm fusion: 339us,
//     but k_fuse=90us ~= additive (bucket blocks dispatch first) + 2.4M LDS
//     bank conflicts (Bs tx*8 stride).
// R6: (a) interleave bucket/gemm blocks (b%3) so atomic-bound and VALU-bound
//     waves co-resident from t=0; (b) hs staged as FP16 (only agg reads it):
//     halves gather bytes + L2 footprint; quarter-wave 16B loads, fp32 accum;
//     (c) b-frag cols remapped to {tx*4, 64+tx*4} => 2-way LDS (free).

constexpr int N = 50000;
constexpr int E = 800000;
constexpr int D = 128;
constexpr int DOUT = 40;
constexpr int CAP = 64;              // bucket capacity (Poisson(16) tail ~1e-18)
constexpr int T4 = E / 4;            // 200000 bucket threads
constexpr int GB = (T4 + 255) / 256; // 782 bucket blocks
constexpr int GM = (N + 127) / 128;  // 391 gemm blocks (GB+GM = 3*GM = 1173)

// ---------------- shared GEMM tile: outH[r] = fp16(A[r] @ W) ----------------
__device__ __forceinline__ void gemm128(const float* __restrict__ A,
                                        const float* __restrict__ W,
                                        __half* __restrict__ outH,
                                        int row0, int tid,
                                        float (*As)[128], float (*Bs)[128]) {
    int tx = tid & 15, ty = tid >> 4;
    float acc[8][8] = {};

    for (int kt = 0; kt < 128; kt += 32) {
        {
            int r = tid >> 1;
            int kk = (tid & 1) * 16;
            int grow = row0 + r;
#pragma unroll
            for (int q = 0; q < 4; ++q) {
                float4 v = make_float4(0.f, 0.f, 0.f, 0.f);
                if (grow < N) v = *(const float4*)&A[(size_t)grow * D + kt + kk + q * 4];
                As[kk + q * 4 + 0][r] = v.x;
                As[kk + q * 4 + 1][r] = v.y;
                As[kk + q * 4 + 2][r] = v.z;
                As[kk + q * 4 + 3][r] = v.w;
            }
        }
        {
            int kb = tid >> 3;
            int cb = (tid & 7) * 16;
#pragma unroll
            for (int q = 0; q < 4; ++q) {
                *(float4*)&Bs[kb][cb + q * 4] =
                    *(const float4*)&W[(size_t)(kt + kb) * D + cb + q * 4];
            }
        }
        __syncthreads();
#pragma unroll
        for (int k = 0; k < 32; ++k) {
            float a[8], bb[8];
            *(float4*)&a[0] = *(const float4*)&As[k][ty * 8];
            *(float4*)&a[4] = *(const float4*)&As[k][ty * 8 + 4];
            *(float4*)&bb[0] = *(const float4*)&Bs[k][tx * 4];         // 2-way, free
            *(float4*)&bb[4] = *(const float4*)&Bs[k][64 + tx * 4];    // 2-way, free
#pragma unroll
            for (int i = 0; i < 8; ++i)
#pragma unroll
                for (int j = 0; j < 8; ++j)
                    acc[i][j] = fmaf(a[i], bb[j], acc[i][j]);
        }
        __syncthreads();
    }

    // cols: j<4 -> tx*4+j ; j>=4 -> 64+tx*4+(j-4). fp16 convert + 8B stores.
#pragma unroll
    for (int i = 0; i < 8; ++i) {
        int r = row0 + ty * 8 + i;
        if (r < N) {
            union { __half2 h[2]; uint2 u; } p0, p1;
            p0.h[0] = __floats2half2_rn(acc[i][0], acc[i][1]);
            p0.h[1] = __floats2half2_rn(acc[i][2], acc[i][3]);
            p1.h[0] = __floats2half2_rn(acc[i][4], acc[i][5]);
            p1.h[1] = __floats2half2_rn(acc[i][6], acc[i][7]);
            *(uint2*)&outH[(size_t)r * D + tx * 4]      = p0.u;
            *(uint2*)&outH[(size_t)r * D + 64 + tx * 4] = p1.u;
        }
    }
}

// ---------------- Fused: bucket-scatter + GEMM layer 1 (interleaved) ------
__global__ __launch_bounds__(256) void k_fuse(const int* __restrict__ ei,
                                              int* __restrict__ cursor,
                                              unsigned short* __restrict__ csr,
                                              const float* __restrict__ A,
                                              const float* __restrict__ W,
                                              __half* __restrict__ outH) {
    __shared__ float As[32][128];
    __shared__ float Bs[32][128];
    int b = blockIdx.x;

    if (b % 3 != 2) {
        // ---- bucket branch: 2 of every 3 blocks ----
        int bb = (b / 3) * 2 + (b % 3);        // 0..781
        int t = bb * 256 + threadIdx.x;
        if (t >= T4) return;
#pragma unroll
        for (int i = 0; i < 4; ++i) {
            int e = t + i * T4;
            int c = ei[E + e];
            int r = ei[e];
            int p = atomicAdd(&cursor[c], 1);
            if (p < CAP) csr[(c << 6) + p] = (unsigned short)r;
        }
        return;
    }
    // ---- gemm branch: 1 of every 3 blocks ----
    gemm128(A, W, outH, (b / 3) * 128, threadIdx.x, As, Bs);
}

// ---------------- Plain GEMM (layer 2) ----------------
__global__ __launch_bounds__(256) void k_gemm(const float* __restrict__ A,
                                              const float* __restrict__ W,
                                              __half* __restrict__ outH) {
    __shared__ float As[32][128];
    __shared__ float Bs[32][128];
    gemm128(A, W, outH, blockIdx.x * 128, threadIdx.x, As, Bs);
}

// ---------------- Aggregation (pull, 1 wave/node, fp16 gather) ------------
// out[c] = relu(dinv[c]*(dinv[c]*h[c] + sum_r dinv[r]*h[r]) + bias)
// quarter-wave qw handles one edge; lane q in [0,16) holds cols q*8..q*8+7.
__device__ __forceinline__ void acc8(float* a, float w, uint4 u) {
    __half2* hp = (__half2*)&u;
#pragma unroll
    for (int i = 0; i < 4; ++i) {
        float2 f = __half22float2(hp[i]);
        a[2 * i]     = fmaf(w, f.x, a[2 * i]);
        a[2 * i + 1] = fmaf(w, f.y, a[2 * i + 1]);
    }
}

__global__ __launch_bounds__(256) void k_agg(const __half* __restrict__ hsH,
                                             const int* __restrict__ deg,
                                             const unsigned short* __restrict__ csr,
                                             const float* __restrict__ bias,
                                             float* __restrict__ outF) {
    int wave = threadIdx.x >> 6;
    int lane = threadIdx.x & 63;
    int qw = lane >> 4;         // 0..3: which edge of a group of 4
    int q  = lane & 15;         // column group: halves q*8..q*8+7
    int c = blockIdx.x * 4 + wave;
    if (c >= N) return;
    int dgRaw = deg[c];
    int dg = dgRaw < CAP ? dgRaw : CAP;
    float dc = rsqrtf((float)(dgRaw + 1));
    int e0 = c << 6;

    float a0[8] = {0, 0, 0, 0, 0, 0, 0, 0};
    float a1[8] = {0, 0, 0, 0, 0, 0, 0, 0};
    if (qw == 0) {              // self loop
        uint4 u = *(const uint4*)&hsH[(size_t)c * D + q * 8];
        acc8(a0, dc, u);
    }

    int j = 0;
    for (; j + 8 <= dg; j += 8) {          // 8 edges/iter, 2 rows in flight/lane
        int r0 = csr[e0 + j + qw];
        int r1 = csr[e0 + j + 4 + qw];
        float w0 = rsqrtf((float)(deg[r0] + 1));
        float w1 = rsqrtf((float)(deg[r1] + 1));
        uint4 u0 = *(const uint4*)&hsH[(size_t)r0 * D + q * 8];
        uint4 u1 = *(const uint4*)&hsH[(size_t)r1 * D + q * 8];
        acc8(a0, w0, u0);
        acc8(a1, w1, u1);
    }
    if (j + 4 <= dg) {
        int r0 = csr[e0 + j + qw];
        float w0 = rsqrtf((float)(deg[r0] + 1));
        uint4 u0 = *(const uint4*)&hsH[(size_t)r0 * D + q * 8];
        acc8(a0, w0, u0);
        j += 4;
    }
    int rem = dg - j;                      // 0..3
    if (qw < rem) {
        int r0 = csr[e0 + j + qw];
        float w0 = rsqrtf((float)(deg[r0] + 1));
        uint4 u0 = *(const uint4*)&hsH[(size_t)r0 * D + q * 8];
        acc8(a0, w0, u0);
    }

#pragma unroll
    for (int t = 0; t < 8; ++t) a0[t] += a1[t];
#pragma unroll
    for (int t = 0; t < 8; ++t) a0[t] += __shfl_xor(a0[t], 16, 64);
#pragma unroll
    for (int t = 0; t < 8; ++t) a0[t] += __shfl_xor(a0[t], 32, 64);

    if (qw == 0) {
        float4 b0 = *(const float4*)&bias[q * 8];
        float4 b1 = *(const float4*)&bias[q * 8 + 4];
        float4 o0, o1;
        o0.x = fmaxf(fmaf(dc, a0[0], b0.x), 0.f);
        o0.y = fmaxf(fmaf(dc, a0[1], b0.y), 0.f);
        o0.z = fmaxf(fmaf(dc, a0[2], b0.z), 0.f);
        o0.w = fmaxf(fmaf(dc, a0[3], b0.w), 0.f);
        o1.x = fmaxf(fmaf(dc, a0[4], b1.x), 0.f);
        o1.y = fmaxf(fmaf(dc, a0[5], b1.y), 0.f);
        o1.z = fmaxf(fmaf(dc, a0[6], b1.z), 0.f);
        o1.w = fmaxf(fmaf(dc, a0[7], b1.w), 0.f);
        *(float4*)&outF[(size_t)c * D + q * 8]     = o0;
        *(float4*)&outF[(size_t)c * D + q * 8 + 4] = o1;
    }
}

// ---------------- Mean pool (stage 1) ----------------
__global__ __launch_bounds__(256) void k_pool(const float* __restrict__ h,
                                              float* __restrict__ gpart) {
    int d = threadIdx.x & 127;
    int half = threadIdx.x >> 7;
    int b = blockIdx.x;                 // 256 blocks
    int per = (N + 255) / 256;          // 196
    int r0 = b * per;
    int r1 = r0 + per;
    if (r1 > N) r1 = N;
    float acc = 0.f;
    for (int r = r0 + half; r < r1; r += 2)
        acc += h[(size_t)r * D + d];
    __shared__ float red[256];
    red[threadIdx.x] = acc;
    __syncthreads();
    if (half == 0) gpart[(size_t)b * D + d] = red[d] + red[128 + d];
}

// ---------------- Final: g = sum(gpart)/N; out = g@Wc + bc  (512 threads)
__global__ __launch_bounds__(512) void k_final(const float* __restrict__ gpart,
                                               const float* __restrict__ Wc,
                                               const float* __restrict__ bc,
                                               float* __restrict__ out) {
    __shared__ float g[D];
    __shared__ float red[512];
    int t = threadIdx.x;
    int d = t & 127, grp = t >> 7;      // 4 groups, 64 partials each
    float s = 0.f;
#pragma unroll 4
    for (int w = grp * 64; w < grp * 64 + 64; ++w)
        s += gpart[(size_t)w * D + d];
    red[t] = s;
    __syncthreads();
    if (grp == 0)
        g[d] = (red[d] + red[128 + d] + red[256 + d] + red[384 + d]) * (1.0f / (float)N);
    __syncthreads();
    if (t < DOUT) {
        float acc = bc[t];
        for (int dd = 0; dd < D; ++dd) acc = fmaf(g[dd], Wc[dd * DOUT + t], acc);
        out[t] = acc;
    }
}

extern "C" void kernel_launch(void* const* d_in, const int* in_sizes, int n_in,
                              void* d_out, int out_size, void* d_ws, size_t ws_size,
                              hipStream_t stream) {
    const float* x  = (const float*)d_in[0];
    const int*   ei = (const int*)d_in[1];
    const float* W1 = (const float*)d_in[2];
    const float* b1 = (const float*)d_in[3];
    const float* W2 = (const float*)d_in[4];
    const float* b2 = (const float*)d_in[5];
    const float* Wc = (const float*)d_in[6];
    const float* bc = (const float*)d_in[7];
    float* out = (float*)d_out;

    char* ws = (char*)d_ws;
    size_t off = 0;
    auto alloc = [&](size_t bytes) {
        void* p = ws + off;
        off += (bytes + 511) & ~(size_t)511;
        return p;
    };
    int*            cursor = (int*)           alloc((size_t)N * 4);       // = deg
    unsigned short* csr    = (unsigned short*)alloc((size_t)N * CAP * 2); // 6.4MB
    __half*         hsH    = (__half*)        alloc((size_t)N * D * 2);   // 12.8MB
    float*          hact   = (float*)         alloc((size_t)N * D * 4);   // 25.6MB
    float*          gpart  = (float*)         alloc((size_t)256 * D * 4);
    (void)ws_size; (void)in_sizes; (void)n_in; (void)out_size;

    hipMemsetAsync(cursor, 0, (size_t)N * 4, stream);

    // fused: bucket (2/3 of blocks) + gemm layer 1 (1/3), interleaved
    k_fuse<<<GB + GM, 256, 0, stream>>>(ei, cursor, csr, x, W1, hsH);

    int gA = (N + 3) / 4;       // 12500
    // layer 1 aggregation: hact = relu(Agg(hsH)+b1)
    k_agg<<<gA, 256, 0, stream>>>(hsH, cursor, csr, b1, hact);
    // layer 2: hsH = fp16(hact @ W2)
    k_gemm<<<GM, 256, 0, stream>>>(hact, W2, hsH);
    // layer 2 aggregation: hact = relu(Agg(hsH)+b2)  (reuses hact)
    k_agg<<<gA, 256, 0, stream>>>(hsH, cursor, csr, b2, hact);
    // pool + classify
    k_pool<<<256, 256, 0, stream>>>(hact, gpart);
    k_final<<<1, 512, 0, stream>>>(gpart, Wc, bc, out);
}

// Round 8
// 254.462 us; speedup vs baseline: 2.7876x; 1.0703x over previous
//
#include <hip/hip_runtime.h>
#include <hip/hip_fp16.h>

// GCN: h1 = relu(Agg(x@W1)+b1); h2 = relu(Agg(h1@W2)+b2); out = mean(h2)@Wc+bc
// norm(r,c)=dinv[r]*dinv[c] factors; dinv = rsqrt(deg+1) inline.
// R1: agg MLP (88->57). R2/R3/R4: atomic ILP/contention/scope — all NEUTRAL or
// worse => scattered global atomics are a hard ~16 G/s ceiling on MI355X.
// R5: one atomic pass + bucket/gemm fusion (339). R6: interleave + fp16 hs +
// LDS fix (272; k_fuse 72 ~= atomic floor + partial overlap).
// R7: ZERO-ATOMIC CSR build: LDS chunk-histograms (k_hist) -> per-node prefix
//     over chunks (k_colscan) -> rank-from-LDS scatter fused with GEMM-1.
//     agg1 output fp16 (gemm2 reads fp16). agg2 reduces straight to pool
//     partials (no 25.6MB h2). LDS tiles padded to 132.

constexpr int N = 50000;
constexpr int E = 800000;
constexpr int D = 128;
constexpr int DOUT = 40;
constexpr int CAP = 64;               // slots/node (Poisson(16) tail ~1e-18)
constexpr int HB = 256;               // histogram chunks
constexpr int EPB = (E + HB - 1) / HB;     // 3125 edges/chunk
constexpr int HW = 12500;             // 50000 bytes = 12500 words
constexpr int GM = (N + 127) / 128;   // 391 gemm blocks
constexpr int NW = N / 4;             // 12500 agg blocks (exact: 4 nodes each)
constexpr int GF = 5 * 131;           // 655: 2/5 scatter (262>=256), 3/5 gemm (393>=391)

// ---------------- Phase A: per-chunk LDS histogram ----------------
__global__ __launch_bounds__(256) void k_hist(const int* __restrict__ col,
                                              unsigned char* __restrict__ hist) {
    __shared__ unsigned int h[HW];
    int b = blockIdx.x, t = threadIdx.x;
    for (int i = t; i < HW; i += 256) h[i] = 0;
    __syncthreads();
    int e0 = b * EPB, e1 = e0 + EPB;
    if (e1 > E) e1 = E;
    for (int e = e0 + t; e < e1; e += 256) {
        int c = col[e];
        atomicAdd(&h[c >> 2], 1u << ((c & 3) * 8));
    }
    __syncthreads();
    unsigned int* out = (unsigned int*)(hist + (size_t)b * 50000);
    for (int i = t; i < HW; i += 256) out[i] = h[i];
}

// ---------------- Phase B: per-node prefix over chunks; deg ----------------
__global__ void k_colscan(unsigned char* __restrict__ hist, int* __restrict__ deg) {
    int c = blockIdx.x * 256 + threadIdx.x;
    if (c >= N) return;
    int sum = 0;
    for (int b = 0; b < HB; ++b) {
        size_t idx = (size_t)b * 50000 + c;
        int v = hist[idx];
        hist[idx] = (unsigned char)sum;   // exclusive prefix (deg<=255 assumed)
        sum += v;
    }
    deg[c] = sum;
}

// ---------------- shared GEMM tile: outH[r] = fp16(A[r] @ W) ----------------
__device__ __forceinline__ float4 ld4(const float* p) { return *(const float4*)p; }
__device__ __forceinline__ float4 ld4(const __half* p) {
    uint2 u = *(const uint2*)p;
    __half2* h = (__half2*)&u;
    float2 a = __half22float2(h[0]), b = __half22float2(h[1]);
    return make_float4(a.x, a.y, b.x, b.y);
}

template <typename TA>
__device__ __forceinline__ void gemm128(const TA* __restrict__ A,
                                        const float* __restrict__ W,
                                        __half* __restrict__ outH,
                                        int row0, int tid,
                                        float (*As)[132], float (*Bs)[132]) {
    int tx = tid & 15, ty = tid >> 4;
    float acc[8][8] = {};

    for (int kt = 0; kt < 128; kt += 32) {
        {
            int r = tid >> 1;
            int kk = (tid & 1) * 16;
            int grow = row0 + r;
#pragma unroll
            for (int q = 0; q < 4; ++q) {
                float4 v = make_float4(0.f, 0.f, 0.f, 0.f);
                if (grow < N) v = ld4(&A[(size_t)grow * D + kt + kk + q * 4]);
                As[kk + q * 4 + 0][r] = v.x;
                As[kk + q * 4 + 1][r] = v.y;
                As[kk + q * 4 + 2][r] = v.z;
                As[kk + q * 4 + 3][r] = v.w;
            }
        }
        {
            int kb = tid >> 3;
            int cb = (tid & 7) * 16;
#pragma unroll
            for (int q = 0; q < 4; ++q) {
                *(float4*)&Bs[kb][cb + q * 4] =
                    *(const float4*)&W[(size_t)(kt + kb) * D + cb + q * 4];
            }
        }
        __syncthreads();
#pragma unroll
        for (int k = 0; k < 32; ++k) {
            float a[8], bb[8];
            *(float4*)&a[0] = *(const float4*)&As[k][ty * 8];
            *(float4*)&a[4] = *(const float4*)&As[k][ty * 8 + 4];
            *(float4*)&bb[0] = *(const float4*)&Bs[k][tx * 4];
            *(float4*)&bb[4] = *(const float4*)&Bs[k][64 + tx * 4];
#pragma unroll
            for (int i = 0; i < 8; ++i)
#pragma unroll
                for (int j = 0; j < 8; ++j)
                    acc[i][j] = fmaf(a[i], bb[j], acc[i][j]);
        }
        __syncthreads();
    }

    // cols: j<4 -> tx*4+j ; j>=4 -> 64+tx*4+(j-4)
#pragma unroll
    for (int i = 0; i < 8; ++i) {
        int r = row0 + ty * 8 + i;
        if (r < N) {
            union { __half2 h[2]; uint2 u; } p0, p1;
            p0.h[0] = __floats2half2_rn(acc[i][0], acc[i][1]);
            p0.h[1] = __floats2half2_rn(acc[i][2], acc[i][3]);
            p1.h[0] = __floats2half2_rn(acc[i][4], acc[i][5]);
            p1.h[1] = __floats2half2_rn(acc[i][6], acc[i][7]);
            *(uint2*)&outH[(size_t)r * D + tx * 4]      = p0.u;
            *(uint2*)&outH[(size_t)r * D + 64 + tx * 4] = p1.u;
        }
    }
}

// ---------------- Phase C fused: rank-scatter + GEMM layer 1 ----------------
__global__ __launch_bounds__(256) void k_fuse(const int* __restrict__ ei,
                                              const unsigned char* __restrict__ hist,
                                              unsigned short* __restrict__ csr,
                                              const float* __restrict__ A,
                                              const float* __restrict__ W,
                                              __half* __restrict__ outH) {
    __shared__ __align__(16) unsigned char smem[50048];  // max(50000, 2*32*132*4)
    int b = blockIdx.x, m = b % 5;

    if (m < 2) {
        // ---- scatter branch: rank from LDS, slot = chunk prefix + rank ----
        int sb = (b / 5) * 2 + m;
        if (sb >= HB) return;
        unsigned int* h = (unsigned int*)smem;
        int t = threadIdx.x;
        for (int i = t; i < HW; i += 256) h[i] = 0;
        __syncthreads();
        const unsigned char* pref = hist + (size_t)sb * 50000;
        int e0 = sb * EPB, e1 = e0 + EPB;
        if (e1 > E) e1 = E;
        for (int e = e0 + t; e < e1; e += 256) {
            int c = ei[E + e];
            int r = ei[e];
            unsigned int old = atomicAdd(&h[c >> 2], 1u << ((c & 3) * 8));
            int rank = (old >> ((c & 3) * 8)) & 0xff;
            int slot = (int)pref[c] + rank;
            if (slot < CAP) csr[(c << 6) + slot] = (unsigned short)r;
        }
        return;
    }
    // ---- gemm branch ----
    int gb = (b / 5) * 3 + (m - 2);
    if (gb >= GM) return;
    float (*As)[132] = (float (*)[132])smem;
    float (*Bs)[132] = (float (*)[132])(smem + 32 * 132 * 4);
    gemm128<float>(A, W, outH, gb * 128, threadIdx.x, As, Bs);
}

// ---------------- Plain GEMM (layer 2, fp16 A) ----------------
__global__ __launch_bounds__(256) void k_gemm(const __half* __restrict__ A,
                                              const float* __restrict__ W,
                                              __half* __restrict__ outH) {
    __shared__ float As[32][132];
    __shared__ float Bs[32][132];
    gemm128<__half>(A, W, outH, blockIdx.x * 128, threadIdx.x, As, Bs);
}

// ---------------- Aggregation core (1 wave/node, fp16 gather) ----------------
// a[8] = dc*h[c] + sum_r dinv[r]*h[r]   (reduced across wave; valid in qw==0)
__device__ __forceinline__ void acc8(float* a, float w, uint4 u) {
    __half2* hp = (__half2*)&u;
#pragma unroll
    for (int i = 0; i < 4; ++i) {
        float2 f = __half22float2(hp[i]);
        a[2 * i]     = fmaf(w, f.x, a[2 * i]);
        a[2 * i + 1] = fmaf(w, f.y, a[2 * i + 1]);
    }
}

__device__ __forceinline__ float agg_core(int c, int lane,
                                          const __half* __restrict__ hsH,
                                          const int* __restrict__ deg,
                                          const unsigned short* __restrict__ csr,
                                          float* a0) {
    int qw = lane >> 4;         // 0..3: edge within group of 4
    int q  = lane & 15;         // column group: halves q*8..q*8+7
    int dgRaw = deg[c];
    int dg = dgRaw < CAP ? dgRaw : CAP;
    float dc = rsqrtf((float)(dgRaw + 1));
    int e0 = c << 6;

    float a1[8] = {0, 0, 0, 0, 0, 0, 0, 0};
#pragma unroll
    for (int t = 0; t < 8; ++t) a0[t] = 0.f;
    if (qw == 0) {              // self loop
        uint4 u = *(const uint4*)&hsH[(size_t)c * D + q * 8];
        acc8(a0, dc, u);
    }

    int j = 0;
    for (; j + 8 <= dg; j += 8) {
        int r0 = csr[e0 + j + qw];
        int r1 = csr[e0 + j + 4 + qw];
        float w0 = rsqrtf((float)(deg[r0] + 1));
        float w1 = rsqrtf((float)(deg[r1] + 1));
        uint4 u0 = *(const uint4*)&hsH[(size_t)r0 * D + q * 8];
        uint4 u1 = *(const uint4*)&hsH[(size_t)r1 * D + q * 8];
        acc8(a0, w0, u0);
        acc8(a1, w1, u1);
    }
    if (j + 4 <= dg) {
        int r0 = csr[e0 + j + qw];
        float w0 = rsqrtf((float)(deg[r0] + 1));
        uint4 u0 = *(const uint4*)&hsH[(size_t)r0 * D + q * 8];
        acc8(a0, w0, u0);
        j += 4;
    }
    int rem = dg - j;
    if (qw < rem) {
        int r0 = csr[e0 + j + qw];
        float w0 = rsqrtf((float)(deg[r0] + 1));
        uint4 u0 = *(const uint4*)&hsH[(size_t)r0 * D + q * 8];
        acc8(a0, w0, u0);
    }

#pragma unroll
    for (int t = 0; t < 8; ++t) a0[t] += a1[t];
#pragma unroll
    for (int t = 0; t < 8; ++t) a0[t] += __shfl_xor(a0[t], 16, 64);
#pragma unroll
    for (int t = 0; t < 8; ++t) a0[t] += __shfl_xor(a0[t], 32, 64);
    return dc;
}

// layer-1 agg: writes fp16 rows (consumed by gemm2)
__global__ __launch_bounds__(256) void k_agg1(const __half* __restrict__ hsH,
                                              const int* __restrict__ deg,
                                              const unsigned short* __restrict__ csr,
                                              const float* __restrict__ bias,
                                              __half* __restrict__ outH) {
    int wave = threadIdx.x >> 6;
    int lane = threadIdx.x & 63;
    int c = blockIdx.x * 4 + wave;          // grid exact: 12500*4 = 50000
    float a0[8];
    float dc = agg_core(c, lane, hsH, deg, csr, a0);
    if ((lane >> 4) == 0) {
        int q = lane & 15;
        union { __half2 h[4]; uint4 u; } p;
#pragma unroll
        for (int i = 0; i < 4; ++i) {
            float x = fmaxf(fmaf(dc, a0[2 * i],     bias[q * 8 + 2 * i]),     0.f);
            float y = fmaxf(fmaf(dc, a0[2 * i + 1], bias[q * 8 + 2 * i + 1]), 0.f);
            p.h[i] = __floats2half2_rn(x, y);
        }
        *(uint4*)&outH[(size_t)c * D + q * 8] = p.u;
    }
}

// layer-2 agg: reduces h2 rows straight into per-block pool partials
__global__ __launch_bounds__(256) void k_agg2(const __half* __restrict__ hsH,
                                              const int* __restrict__ deg,
                                              const unsigned short* __restrict__ csr,
                                              const float* __restrict__ bias,
                                              float* __restrict__ gpart) {
    __shared__ float gblk[4][128];
    int wave = threadIdx.x >> 6;
    int lane = threadIdx.x & 63;
    int c = blockIdx.x * 4 + wave;
    float a0[8];
    float dc = agg_core(c, lane, hsH, deg, csr, a0);
    if ((lane >> 4) == 0) {
        int q = lane & 15;
#pragma unroll
        for (int i = 0; i < 8; ++i)
            gblk[wave][q * 8 + i] = fmaxf(fmaf(dc, a0[i], bias[q * 8 + i]), 0.f);
    }
    __syncthreads();
    int t = threadIdx.x;
    if (t < 128)
        gpart[(size_t)blockIdx.x * 128 + t] =
            gblk[0][t] + gblk[1][t] + gblk[2][t] + gblk[3][t];
}

// ---------------- Pool stage 2: 12500 partials -> 256 partials ----------------
__global__ __launch_bounds__(256) void k_pool(const float* __restrict__ gpart,
                                              float* __restrict__ gpart2) {
    int d = threadIdx.x & 127;
    int half = threadIdx.x >> 7;
    int b = blockIdx.x;                 // 256 blocks
    int per = (NW + 255) / 256;         // 49
    int r0 = b * per;
    int r1 = r0 + per;
    if (r1 > NW) r1 = NW;
    float acc = 0.f;
    for (int r = r0 + half; r < r1; r += 2)
        acc += gpart[(size_t)r * D + d];
    __shared__ float red[256];
    red[threadIdx.x] = acc;
    __syncthreads();
    if (half == 0) gpart2[(size_t)b * D + d] = red[d] + red[128 + d];
}

// ---------------- Final: g = sum(gpart2)/N; out = g@Wc + bc ----------------
__global__ __launch_bounds__(512) void k_final(const float* __restrict__ gpart2,
                                               const float* __restrict__ Wc,
                                               const float* __restrict__ bc,
                                               float* __restrict__ out) {
    __shared__ float g[D];
    __shared__ float red[512];
    int t = threadIdx.x;
    int d = t & 127, grp = t >> 7;      // 4 groups, 64 partials each
    float s = 0.f;
#pragma unroll 4
    for (int w = grp * 64; w < grp * 64 + 64; ++w)
        s += gpart2[(size_t)w * D + d];
    red[t] = s;
    __syncthreads();
    if (grp == 0)
        g[d] = (red[d] + red[128 + d] + red[256 + d] + red[384 + d]) * (1.0f / (float)N);
    __syncthreads();
    if (t < DOUT) {
        float acc = bc[t];
        for (int dd = 0; dd < D; ++dd) acc = fmaf(g[dd], Wc[dd * DOUT + t], acc);
        out[t] = acc;
    }
}

extern "C" void kernel_launch(void* const* d_in, const int* in_sizes, int n_in,
                              void* d_out, int out_size, void* d_ws, size_t ws_size,
                              hipStream_t stream) {
    const float* x  = (const float*)d_in[0];
    const int*   ei = (const int*)d_in[1];
    const float* W1 = (const float*)d_in[2];
    const float* b1 = (const float*)d_in[3];
    const float* W2 = (const float*)d_in[4];
    const float* b2 = (const float*)d_in[5];
    const float* Wc = (const float*)d_in[6];
    const float* bc = (const float*)d_in[7];
    float* out = (float*)d_out;

    char* ws = (char*)d_ws;
    size_t off = 0;
    auto alloc = [&](size_t bytes) {
        void* p = ws + off;
        off += (bytes + 511) & ~(size_t)511;
        return p;
    };
    unsigned char*  hist   = (unsigned char*) alloc((size_t)HB * 50000);     // 12.8MB
    int*            deg    = (int*)           alloc((size_t)N * 4);
    unsigned short* csr    = (unsigned short*)alloc((size_t)N * CAP * 2);    // 6.4MB
    __half*         hsH    = (__half*)        alloc((size_t)N * D * 2);      // 12.8MB
    __half*         hactH  = (__half*)        alloc((size_t)N * D * 2);      // 12.8MB
    float*          gpart  = (float*)         alloc((size_t)NW * D * 4);     // 6.4MB
    float*          gpart2 = (float*)         alloc((size_t)256 * D * 4);
    (void)ws_size; (void)in_sizes; (void)n_in; (void)out_size;

    const int* col = ei + E;

    // zero-atomic CSR build
    k_hist<<<HB, 256, 0, stream>>>(col, hist);
    k_colscan<<<(N + 255) / 256, 256, 0, stream>>>(hist, deg);
    // scatter (2/5) + gemm layer 1 (3/5), interleaved
    k_fuse<<<GF, 256, 0, stream>>>(ei, hist, csr, x, W1, hsH);

    // layer 1 aggregation -> fp16 rows
    k_agg1<<<NW, 256, 0, stream>>>(hsH, deg, csr, b1, hactH);
    // layer 2 gemm (fp16 A)
    k_gemm<<<GM, 256, 0, stream>>>(hactH, W2, hsH);
    // layer 2 aggregation -> pool partials
    k_agg2<<<NW, 256, 0, stream>>>(hsH, deg, csr, b2, gpart);
    // pool + classify
    k_pool<<<256, 256, 0, stream>>>(gpart, gpart2);
    k_final<<<1, 512, 0, stream>>>(gpart2, Wc, bc, out);
}